// Round 3
// baseline (568.410 us; speedup 1.0000x reference)
//
#include <hip/hip_runtime.h>
#include <math.h>

#define Bsz 1024
#define Tt  128
#define Ff  32
#define Ee  16
#define Hh  20
#define Dd  4096
#define EPSc 1e-3f
#define LOG2E 1.4426950408889634f

// repacked fp32 weights per expert, gate-interleaved cols c = 4*u + g (g: i,f,g,o):
// K1p[32][80]@0, R1p[20][80]@2560, K2p[20][80]@4160, R2p[20][80]@5760,
// b1p[80]@7360, b2p[80]@7440  -> 7520 floats per expert
// i/f/o gate columns (g != 2) are pre-scaled by log2(e) so sigmoid uses exp2 directly.
#define PWE 7520

typedef __attribute__((ext_vector_type(8))) short bf16x8;
typedef __attribute__((ext_vector_type(4))) float f32x4;
typedef __attribute__((ext_vector_type(4))) unsigned int u32x4;

#define MFMA16(a,b,c) __builtin_amdgcn_mfma_f32_16x16x32_bf16(a, b, c, 0, 0, 0)

__device__ __forceinline__ float sig2(float z) {      // z already scaled by log2(e)
    // raw v_exp_f32 + v_rcp_f32: ~1ulp each, large |z| saturates correctly (inf->0, 0->1)
    return __builtin_amdgcn_rcpf(1.0f + __builtin_amdgcn_exp2f(-z));
}
__device__ __forceinline__ unsigned short bf16_rne(float f) {
    unsigned u = __float_as_uint(f);
    u += 0x7FFFu + ((u >> 16) & 1u);
    return (unsigned short)(u >> 16);
}
__device__ __forceinline__ float bf16_to_f(unsigned short h) {
    return __uint_as_float(((unsigned)h) << 16);
}
// split 2 floats into packed-bf16 hi word + packed-bf16 lo word, RNE both
// (identical numerics to bf16_rne path; v_cvt_pk_bf16_f32 is RNE).
__device__ __forceinline__ void cvt2(float f0, float f1, unsigned& hp, unsigned& lp) {
    asm("v_cvt_pk_bf16_f32 %0, %1, %2" : "=v"(hp) : "v"(f0), "v"(f1));
    float h0 = __uint_as_float(hp << 16);
    float h1 = __uint_as_float(hp & 0xFFFF0000u);
    asm("v_cvt_pk_bf16_f32 %0, %1, %2" : "=v"(lp) : "v"(f0 - h0), "v"(f1 - h1));
}

// ---------------------------------------------------------------- x prepass: BN + bf16 hi/lo split
// into per-(chunk,t,lane) fragment layout: elem (c,t,l)*8 holds xn[c*16+s][t][q*8..+8]
__global__ void xpack_kernel(const float* __restrict__ x,
                             const float* __restrict__ gamma, const float* __restrict__ beta,
                             const float* __restrict__ mean,  const float* __restrict__ var,
                             unsigned short* __restrict__ xph, unsigned short* __restrict__ xpl)
{
    __shared__ float sc[Ff], sh[Ff];
    int tid = threadIdx.x;
    if (tid < Ff) {
        float s = gamma[tid] * rsqrtf(var[tid] + EPSc);
        sc[tid] = s;
        sh[tid] = beta[tid] - mean[tid] * s;
    }
    __syncthreads();
    int idx = blockIdx.x * 256 + tid;           // 0 .. 64*128*64-1
    int c   = idx >> 13;
    int rem = idx & 8191;
    int t   = rem >> 6;
    int l   = rem & 63;
    int q   = l >> 4, s = l & 15;
    const float* xr = x + ((size_t)(c * 16 + s) * Tt + t) * Ff + q * 8;
    float4 v0 = *(const float4*)xr;
    float4 v1 = *(const float4*)(xr + 4);
    float xv[8] = {v0.x, v0.y, v0.z, v0.w, v1.x, v1.y, v1.z, v1.w};
    bf16x8 hv, lv;
#pragma unroll
    for (int j = 0; j < 8; ++j) {
        int f = q * 8 + j;
        float xn_ = xv[j] * sc[f] + sh[f];
        unsigned short hi = bf16_rne(xn_);
        hv[j] = (short)hi;
        lv[j] = (short)bf16_rne(xn_ - bf16_to_f(hi));
    }
    *(bf16x8*)(xph + (size_t)idx * 8) = hv;
    *(bf16x8*)(xpl + (size_t)idx * 8) = lv;
}

// ---------------------------------------------------------------- weight repack (gate-interleave)
__global__ void repack2_kernel(const float* __restrict__ k1, const float* __restrict__ r1,
                               const float* __restrict__ b1, const float* __restrict__ k2,
                               const float* __restrict__ r2, const float* __restrict__ b2,
                               float* __restrict__ pw)
{
    int idx = blockIdx.x * blockDim.x + threadIdx.x;
    if (idx >= Ee * PWE) return;
    int e = idx / PWE;
    int o = idx % PWE;
    float v;
    int g;
    if (o < 7360) {
        int c = o % 80, u = c >> 2;
        g = c & 3;
        int co = g * 20 + u;
        if (o < 2560) {
            int kk = o / 80;
            v = k1[((size_t)e * Ff + kk) * 80 + co];
        } else if (o < 4160) {
            int kk = (o - 2560) / 80;
            v = r1[((size_t)e * Hh + kk) * 80 + co];
        } else if (o < 5760) {
            int kk = (o - 4160) / 80;
            v = k2[((size_t)e * Hh + kk) * 80 + co];
        } else {
            int kk = (o - 5760) / 80;
            v = r2[((size_t)e * Hh + kk) * 80 + co];
        }
    } else if (o < 7440) {
        int c = o - 7360, u = c >> 2;
        g = c & 3;
        v = b1[(size_t)e * 80 + g * 20 + u];
    } else {
        int c = o - 7440, u = c >> 2;
        g = c & 3;
        v = b2[(size_t)e * 80 + g * 20 + u];
    }
    if (g != 2) v *= LOG2E;     // sigmoid gates -> exp2 domain
    pw[idx] = v;
}

// ---------------------------------------------------------------- fused lstm + fc1
// 512 blocks x 256 thr, 2 blocks/CU. Dispatch maps block i and i+256 to the SAME CU
// (round-robin over 8 XCDs x 32 CUs), so the selector is blockIdx.x<256: each CU gets
// one latency-bound LSTM block + one throughput-bound fc1 block (m114 co-scheduling).
//
// LSTM: swapped-operand MFMA (mfma(W,x) -> z^T): lane(q,s) reg r = gate r of unit
// 4n+q, batch s. The h-recurrence uses a PERMUTED k-map for R1/K2/R2: B-fragment
// slot (q,j) = unit 4j+q (instead of 8q+j). MFMA contraction is symmetric in k, so
// permuting k on BOTH the weight fragment (repack index uk=4j+q) and the h fragment
// preserves the result -- and with this map, lane (q,s)'s B-elements are exactly the
// h values it computed itself (unit 4n+q -> slot j=n). h never touches LDS: packed
// in-register with cvt_pk. LSTM uses ZERO shared memory, no LDS latency walls.
__global__ __launch_bounds__(256, 2) void fused_kernel(
    const unsigned short* __restrict__ xph, const unsigned short* __restrict__ xpl,
    const float* __restrict__ pw, const float* __restrict__ dw, const float* __restrict__ db,
    float* __restrict__ eo,
    const float* __restrict__ x, const float* __restrict__ W,
    const float* __restrict__ bias, float* __restrict__ C)
{
    __shared__ __align__(16) char smem[43008];

    if (blockIdx.x < 256) {
        // ================= LSTM path: wave w handles tile blockIdx.x*4+w =================
        const int l = threadIdx.x & 63;
        const int q = l >> 4, s = l & 15;
        const int tile = (blockIdx.x << 2) + (threadIdx.x >> 6);
        const int e = tile >> 6;
        const int c = tile & 63;
        const int b0 = c * 16;

        const float* Wm = pw + (size_t)e * PWE;
        bf16x8 K1h[5], K1l[5], R1h[5], R1l[5], K2h[5], K2l[5], R2h[5], R2l[5];
#pragma unroll
        for (int n = 0; n < 5; ++n) {
#pragma unroll
            for (int j = 0; j < 8; ++j) {
                int k8 = q * 8 + j;         // K1: x-feature k-map (32 features)
                int uk = 4 * j + q;         // R1/K2/R2: permuted h-unit k-map (j<5 valid)
                int cc = n * 16 + s;
                float wv_;
                unsigned short hi; float hf;
                wv_ = Wm[k8 * 80 + cc];
                hi = bf16_rne(wv_); hf = bf16_to_f(hi);
                K1h[n][j] = (short)hi; K1l[n][j] = (short)bf16_rne(wv_ - hf);
                wv_ = (j < 5) ? Wm[2560 + uk * 80 + cc] : 0.f;
                hi = bf16_rne(wv_); hf = bf16_to_f(hi);
                R1h[n][j] = (short)hi; R1l[n][j] = (short)bf16_rne(wv_ - hf);
                wv_ = (j < 5) ? Wm[4160 + uk * 80 + cc] : 0.f;
                hi = bf16_rne(wv_); hf = bf16_to_f(hi);
                K2h[n][j] = (short)hi; K2l[n][j] = (short)bf16_rne(wv_ - hf);
                wv_ = (j < 5) ? Wm[5760 + uk * 80 + cc] : 0.f;
                hi = bf16_rne(wv_); hf = bf16_to_f(hi);
                R2h[n][j] = (short)hi; R2l[n][j] = (short)bf16_rne(wv_ - hf);
            }
        }
        // bias in C-layout of the swapped MFMA: reg r <-> gatecol 16n+4q+r (contiguous)
        f32x4 bf1[5], bf2[5];
        float dwr[5];
#pragma unroll
        for (int n = 0; n < 5; ++n) {
            bf1[n] = *(const f32x4*)&Wm[7360 + n * 16 + 4 * q];
            bf2[n] = *(const f32x4*)&Wm[7440 + n * 16 + 4 * q];
            dwr[n] = dw[e * Hh + 4 * n + q];
        }

        float c1[5] = {0, 0, 0, 0, 0}, c2[5] = {0, 0, 0, 0, 0};
        float h2reg[5] = {0, 0, 0, 0, 0};

        const bf16x8 z8 = {0, 0, 0, 0, 0, 0, 0, 0};
        bf16x8 H1a = z8, H1b = z8, H2a = z8, H2b = z8;   // h[t-1] fragments, reg-resident

        const unsigned short* xbh = xph + (size_t)c * 65536 + l * 8;
        const unsigned short* xbl = xpl + (size_t)c * 65536 + l * 8;
        bf16x8 xch = *(const bf16x8*)xbh;
        bf16x8 xcl = *(const bf16x8*)xbl;

#pragma unroll 1
        for (int t = 0; t < Tt; ++t) {
            bf16x8 xnh = xch, xnl = xcl;
            if (t < Tt - 1) {       // prefetch t+1 (overlaps this step's compute)
                xnh = *(const bf16x8*)(xbh + (t + 1) * 512);
                xnl = *(const bf16x8*)(xbl + (t + 1) * 512);
            }

            // ---- layer 1: z^T = K1^T x^T + R1^T h1^T
            f32x4 a1[5];
#pragma unroll
            for (int n = 0; n < 5; ++n) {
                f32x4 acc = bf1[n];
                acc = MFMA16(K1h[n], xch, acc);
                acc = MFMA16(K1l[n], xch, acc);
                acc = MFMA16(K1h[n], xcl, acc);
                acc = MFMA16(R1h[n], H1a, acc);
                acc = MFMA16(R1l[n], H1a, acc);
                acc = MFMA16(R1h[n], H1b, acc);
                a1[n] = acc;
            }
            // activation + in-register h1 fragment pack (unit 4n+q -> slot j=n)
            {
                float hv[5];
#pragma unroll
                for (int n = 0; n < 5; ++n) {
                    float iv = sig2(a1[n][0]);
                    float fv = sig2(a1[n][1]);
                    float gv = fmaxf(a1[n][2], 0.f);
                    float ov = sig2(a1[n][3]);
                    c1[n] = fv * c1[n] + iv * gv;
                    hv[n] = ov * fmaxf(c1[n], 0.f);
                }
                unsigned h0, h1, h2, l0, l1, l2;
                cvt2(hv[0], hv[1], h0, l0);
                cvt2(hv[2], hv[3], h1, l1);
                cvt2(hv[4], 0.f,   h2, l2);
                u32x4 uh = {h0, h1, h2, 0u}, ul = {l0, l1, l2, 0u};
                H1a = __builtin_bit_cast(bf16x8, uh);
                H1b = __builtin_bit_cast(bf16x8, ul);
            }

            // ---- layer 2 (K2 contracts h1 with the same permuted k-map)
            f32x4 a2[5];
#pragma unroll
            for (int n = 0; n < 5; ++n) {
                f32x4 acc = bf2[n];
                acc = MFMA16(K2h[n], H1a, acc);
                acc = MFMA16(K2l[n], H1a, acc);
                acc = MFMA16(K2h[n], H1b, acc);
                acc = MFMA16(R2h[n], H2a, acc);
                acc = MFMA16(R2l[n], H2a, acc);
                acc = MFMA16(R2h[n], H2b, acc);
                a2[n] = acc;
            }
            {
                float hv[5];
#pragma unroll
                for (int n = 0; n < 5; ++n) {
                    float iv = sig2(a2[n][0]);
                    float fv = sig2(a2[n][1]);
                    float gv = fmaxf(a2[n][2], 0.f);
                    float ov = sig2(a2[n][3]);
                    c2[n] = fv * c2[n] + iv * gv;
                    float h = ov * fmaxf(c2[n], 0.f);
                    h2reg[n] = h;
                    hv[n] = h;
                }
                unsigned h0, h1, h2, l0, l1, l2;
                cvt2(hv[0], hv[1], h0, l0);
                cvt2(hv[2], hv[3], h1, l1);
                cvt2(hv[4], 0.f,   h2, l2);
                u32x4 uh = {h0, h1, h2, 0u}, ul = {l0, l1, l2, 0u};
                H2a = __builtin_bit_cast(bf16x8, uh);
                H2b = __builtin_bit_cast(bf16x8, ul);
            }

            xch = xnh; xcl = xnl;
        }

        float p = 0.f;
#pragma unroll
        for (int n = 0; n < 5; ++n) p += h2reg[n] * dwr[n];
        p += __shfl_xor(p, 16);
        p += __shfl_xor(p, 32);
        if (q == 0) eo[(size_t)e * Bsz + b0 + s] = db[e] + p;

    } else {
        // ================= fc1 path: 128x128 split-bf16 MFMA tile =================
        // row stride 42 shorts (84B = 21 banks, odd) -> fragment-read start banks
        // (21s+4q) mod 32 spread over 16+ distinct banks (~2-way max, free per m136)
        unsigned short* Ash = (unsigned short*)smem;      // 128*42 each
        unsigned short* Asl = Ash + 5376;
        unsigned short* Wsh = Asl + 5376;
        unsigned short* Wsl = Wsh + 5376;

        const int tid = threadIdx.x;
        const int wv = tid >> 6, l = tid & 63, q = l >> 4, s = l & 15;
        const int id = blockIdx.x & 255;
        const int n0 = (id & 31) * 128, m0 = (id >> 5) * 128;
        const int wr = (wv & 1) * 64, wc = (wv >> 1) * 64;

        const int am = tid >> 1, ak = (tid & 1) * 16;
        const int wn = tid & 127, wkq = tid >> 7;

        const float* AG = x + (size_t)(m0 + am) * Dd + ak;
        const float* WG = W + (size_t)(wkq * 16) * Dd + n0 + wn;

        f32x4 acc[4][4];
#pragma unroll
        for (int mt = 0; mt < 4; ++mt)
#pragma unroll
            for (int nt = 0; nt < 4; ++nt) acc[mt][nt] = (f32x4){0.f, 0.f, 0.f, 0.f};

        float af[16], wf[16];
#pragma unroll
        for (int i = 0; i < 4; ++i) *(float4*)&af[i * 4] = *(const float4*)(AG + i * 4);
#pragma unroll
        for (int i = 0; i < 16; ++i) wf[i] = WG[(size_t)i * Dd];

#pragma unroll 1
        for (int k0 = 0; k0 < Dd; k0 += 32) {
            __syncthreads();
            {   // A tile: v_cvt_pk split (3 VALU/elem), single 16B LDS stores
                uint4 h0, l0, h1, l1;
                cvt2(af[0],  af[1],  h0.x, l0.x); cvt2(af[2],  af[3],  h0.y, l0.y);
                cvt2(af[4],  af[5],  h0.z, l0.z); cvt2(af[6],  af[7],  h0.w, l0.w);
                cvt2(af[8],  af[9],  h1.x, l1.x); cvt2(af[10], af[11], h1.y, l1.y);
                cvt2(af[12], af[13], h1.z, l1.z); cvt2(af[14], af[15], h1.w, l1.w);
                *(uint4*)&Ash[am * 42 + ak]     = h0;
                *(uint4*)&Asl[am * 42 + ak]     = l0;
                *(uint4*)&Ash[am * 42 + ak + 8] = h1;
                *(uint4*)&Asl[am * 42 + ak + 8] = l1;
            }
            {   // W tile: same
                uint4 h0, l0, h1, l1;
                cvt2(wf[0],  wf[1],  h0.x, l0.x); cvt2(wf[2],  wf[3],  h0.y, l0.y);
                cvt2(wf[4],  wf[5],  h0.z, l0.z); cvt2(wf[6],  wf[7],  h0.w, l0.w);
                cvt2(wf[8],  wf[9],  h1.x, l1.x); cvt2(wf[10], wf[11], h1.y, l1.y);
                cvt2(wf[12], wf[13], h1.z, l1.z); cvt2(wf[14], wf[15], h1.w, l1.w);
                *(uint4*)&Wsh[wn * 42 + wkq * 16]     = h0;
                *(uint4*)&Wsl[wn * 42 + wkq * 16]     = l0;
                *(uint4*)&Wsh[wn * 42 + wkq * 16 + 8] = h1;
                *(uint4*)&Wsl[wn * 42 + wkq * 16 + 8] = l1;
            }
            __syncthreads();

            if (k0 + 32 < Dd) {
                const float* ag = AG + k0 + 32;
                const float* wg = WG + (size_t)(k0 + 32) * Dd;
#pragma unroll
                for (int i = 0; i < 4; ++i) *(float4*)&af[i * 4] = *(const float4*)(ag + i * 4);
#pragma unroll
                for (int i = 0; i < 16; ++i) wf[i] = wg[(size_t)i * Dd];
            }

            bf16x8 Afh[4], Afl[4], Wfh[4], Wfl[4];
#pragma unroll
            for (int mt = 0; mt < 4; ++mt) {
                Afh[mt] = *(bf16x8*)&Ash[(wr + mt * 16 + s) * 42 + q * 8];
                Afl[mt] = *(bf16x8*)&Asl[(wr + mt * 16 + s) * 42 + q * 8];
            }
#pragma unroll
            for (int nt = 0; nt < 4; ++nt) {
                Wfh[nt] = *(bf16x8*)&Wsh[(wc + nt * 16 + s) * 42 + q * 8];
                Wfl[nt] = *(bf16x8*)&Wsl[(wc + nt * 16 + s) * 42 + q * 8];
            }
#pragma unroll
            for (int mt = 0; mt < 4; ++mt)
#pragma unroll
                for (int nt = 0; nt < 4; ++nt) {
                    f32x4 a = acc[mt][nt];
                    a = MFMA16(Afl[mt], Wfh[nt], a);
                    a = MFMA16(Afh[mt], Wfl[nt], a);
                    a = MFMA16(Afh[mt], Wfh[nt], a);
                    acc[mt][nt] = a;
                }
        }

#pragma unroll
        for (int nt = 0; nt < 4; ++nt) {
            float bv = bias[n0 + wc + nt * 16 + s];
#pragma unroll
            for (int mt = 0; mt < 4; ++mt)
#pragma unroll
                for (int r = 0; r < 4; ++r) {
                    int m = m0 + wr + mt * 16 + q * 4 + r;
                    C[(size_t)m * Dd + n0 + wc + nt * 16 + s] = fmaxf(acc[mt][nt][r] + bv, 0.f);
                }
        }
    }
}

// ---------------------------------------------------------------- gate: softmax(g @ gate_w + gb) + combine
__global__ __launch_bounds__(256) void gate_kernel(const float* __restrict__ g,
                                                   const float* __restrict__ gw,
                                                   const float* __restrict__ gb,
                                                   const float* __restrict__ eo,
                                                   float* __restrict__ out)
{
    int b = blockIdx.x;
    int tid = threadIdx.x;
    int lane = tid & 63;
    int wv = tid >> 6;

    float acc[16];
#pragma unroll
    for (int j = 0; j < 16; ++j) acc[j] = 0.f;

    const float* grow = g + (size_t)b * Dd;
#pragma unroll
    for (int it = 0; it < Dd / 256; ++it) {
        int d = tid + it * 256;
        float gv = grow[d];
        const float4* wr = (const float4*)(gw + (size_t)d * 16);
        float4 w0 = wr[0], w1 = wr[1], w2 = wr[2], w3 = wr[3];
        acc[0] += gv * w0.x;  acc[1] += gv * w0.y;  acc[2] += gv * w0.z;  acc[3] += gv * w0.w;
        acc[4] += gv * w1.x;  acc[5] += gv * w1.y;  acc[6] += gv * w1.z;  acc[7] += gv * w1.w;
        acc[8] += gv * w2.x;  acc[9] += gv * w2.y;  acc[10] += gv * w2.z; acc[11] += gv * w2.w;
        acc[12] += gv * w3.x; acc[13] += gv * w3.y; acc[14] += gv * w3.z; acc[15] += gv * w3.w;
    }

    __shared__ float red[64];
    __shared__ float logits[16];
#pragma unroll
    for (int j = 0; j < 16; ++j) {
        float v = acc[j];
#pragma unroll
        for (int m = 32; m >= 1; m >>= 1) v += __shfl_xor(v, m);
        if (lane == 0) red[wv * 16 + j] = v;
    }
    __syncthreads();
    if (tid < 16) {
        logits[tid] = gb[tid] + red[tid] + red[16 + tid] + red[32 + tid] + red[48 + tid];
    }
    __syncthreads();
    if (tid == 0) {
        float m = logits[0];
#pragma unroll
        for (int j = 1; j < 16; ++j) m = fmaxf(m, logits[j]);
        float ex[16], ssum = 0.f;
#pragma unroll
        for (int j = 0; j < 16; ++j) { ex[j] = __expf(logits[j] - m); ssum += ex[j]; }
        float inv = 1.f / ssum;
        float o = 0.f;
#pragma unroll
        for (int j = 0; j < 16; ++j) o += ex[j] * inv * eo[(size_t)j * Bsz + b];
        out[b] = o;
    }
}

// ----------------------------------------------------------------
extern "C" void kernel_launch(void* const* d_in, const int* in_sizes, int n_in,
                              void* d_out, int out_size, void* d_ws, size_t ws_size,
                              hipStream_t stream)
{
    const float* x     = (const float*)d_in[0];
    const float* gamma = (const float*)d_in[1];
    const float* beta  = (const float*)d_in[2];
    const float* mean  = (const float*)d_in[3];
    const float* var   = (const float*)d_in[4];
    const float* k1    = (const float*)d_in[5];
    const float* r1    = (const float*)d_in[6];
    const float* b1    = (const float*)d_in[7];
    const float* k2    = (const float*)d_in[8];
    const float* r2    = (const float*)d_in[9];
    const float* b2    = (const float*)d_in[10];
    const float* dw    = (const float*)d_in[11];
    const float* db    = (const float*)d_in[12];
    const float* fc1w  = (const float*)d_in[13];
    const float* fc1b  = (const float*)d_in[14];
    const float* gw    = (const float*)d_in[15];
    const float* gb    = (const float*)d_in[16];
    float* out = (float*)d_out;

    // workspace: 33.1 MB (<= previously-proven 34.2 MB footprint)
    float* g = (float*)d_ws;                                        // 4,194,304 f (16 MB)
    unsigned short* xph = (unsigned short*)(g + (size_t)Bsz * Dd);  // 4,194,304 us (8 MB)
    unsigned short* xpl = xph + (size_t)Bsz * Dd / 2 * 2;           // 8 MB (same count)
    float* pw  = (float*)(xpl + (size_t)4194304);                   // 120,320 f
    float* eo  = pw + (size_t)Ee * PWE;                             // 16,384 f

    xpack_kernel<<<2048, 256, 0, stream>>>(x, gamma, beta, mean, var, xph, xpl);
    repack2_kernel<<<(Ee * PWE + 255) / 256, 256, 0, stream>>>(k1, r1, b1, k2, r2, b2, pw);
    fused_kernel<<<512, 256, 0, stream>>>(xph, xpl, pw, dw, db, eo, x, fc1w, fc1b, g);
    gate_kernel<<<Bsz, 256, 0, stream>>>(g, gw, gb, eo, out);
}

// Round 4
// 467.475 us; speedup vs baseline: 1.2159x; 1.2159x over previous
//
#include <hip/hip_runtime.h>
#include <math.h>

#define Bsz 1024
#define Tt  128
#define Ff  32
#define Ee  16
#define Hh  20
#define Dd  4096
#define EPSc 1e-3f
#define LOG2E 1.4426950408889634f

// repacked fp32 weights per expert, gate-interleaved cols c = 4*u + g (g: i,f,g,o):
// K1p[32][80]@0, R1p[20][80]@2560, K2p[20][80]@4160, R2p[20][80]@5760,
// b1p[80]@7360, b2p[80]@7440  -> 7520 floats per expert
// i/f/o gate columns (g != 2) are pre-scaled by log2(e) so sigmoid uses exp2 directly.
#define PWE 7520

typedef __attribute__((ext_vector_type(8))) short bf16x8;
typedef __attribute__((ext_vector_type(4))) float f32x4;
typedef __attribute__((ext_vector_type(4))) unsigned int u32x4;

#define MFMA16(a,b,c) __builtin_amdgcn_mfma_f32_16x16x32_bf16(a, b, c, 0, 0, 0)

__device__ __forceinline__ float sig2(float z) {      // z already scaled by log2(e)
    return __builtin_amdgcn_rcpf(1.0f + __builtin_amdgcn_exp2f(-z));
}
__device__ __forceinline__ unsigned short bf16_rne(float f) {
    unsigned u = __float_as_uint(f);
    u += 0x7FFFu + ((u >> 16) & 1u);
    return (unsigned short)(u >> 16);
}
__device__ __forceinline__ float bf16_to_f(unsigned short h) {
    return __uint_as_float(((unsigned)h) << 16);
}
// split 2 floats into packed-bf16 hi word + packed-bf16 lo word, RNE both
// (identical numerics to bf16_rne path; v_cvt_pk_bf16_f32 is RNE).
__device__ __forceinline__ void cvt2(float f0, float f1, unsigned& hp, unsigned& lp) {
    asm("v_cvt_pk_bf16_f32 %0, %1, %2" : "=v"(hp) : "v"(f0), "v"(f1));
    float h0 = __uint_as_float(hp << 16);
    float h1 = __uint_as_float(hp & 0xFFFF0000u);
    asm("v_cvt_pk_bf16_f32 %0, %1, %2" : "=v"(lp) : "v"(f0 - h0), "v"(f1 - h1));
}

// ---------------------------------------------------------------- x prepass: BN + bf16 hi/lo split
__global__ void xpack_kernel(const float* __restrict__ x,
                             const float* __restrict__ gamma, const float* __restrict__ beta,
                             const float* __restrict__ mean,  const float* __restrict__ var,
                             unsigned short* __restrict__ xph, unsigned short* __restrict__ xpl)
{
    __shared__ float sc[Ff], sh[Ff];
    int tid = threadIdx.x;
    if (tid < Ff) {
        float s = gamma[tid] * rsqrtf(var[tid] + EPSc);
        sc[tid] = s;
        sh[tid] = beta[tid] - mean[tid] * s;
    }
    __syncthreads();
    int idx = blockIdx.x * 256 + tid;           // 0 .. 64*128*64-1
    int c   = idx >> 13;
    int rem = idx & 8191;
    int t   = rem >> 6;
    int l   = rem & 63;
    int q   = l >> 4, s = l & 15;
    const float* xr = x + ((size_t)(c * 16 + s) * Tt + t) * Ff + q * 8;
    float4 v0 = *(const float4*)xr;
    float4 v1 = *(const float4*)(xr + 4);
    float xv[8] = {v0.x, v0.y, v0.z, v0.w, v1.x, v1.y, v1.z, v1.w};
    bf16x8 hv, lv;
#pragma unroll
    for (int j = 0; j < 8; ++j) {
        int f = q * 8 + j;
        float xn_ = xv[j] * sc[f] + sh[f];
        unsigned short hi = bf16_rne(xn_);
        hv[j] = (short)hi;
        lv[j] = (short)bf16_rne(xn_ - bf16_to_f(hi));
    }
    *(bf16x8*)(xph + (size_t)idx * 8) = hv;
    *(bf16x8*)(xpl + (size_t)idx * 8) = lv;
}

// ---------------------------------------------------------------- weight repack (gate-interleave)
__global__ void repack2_kernel(const float* __restrict__ k1, const float* __restrict__ r1,
                               const float* __restrict__ b1, const float* __restrict__ k2,
                               const float* __restrict__ r2, const float* __restrict__ b2,
                               float* __restrict__ pw)
{
    int idx = blockIdx.x * blockDim.x + threadIdx.x;
    if (idx >= Ee * PWE) return;
    int e = idx / PWE;
    int o = idx % PWE;
    float v;
    int g;
    if (o < 7360) {
        int c = o % 80, u = c >> 2;
        g = c & 3;
        int co = g * 20 + u;
        if (o < 2560) {
            int kk = o / 80;
            v = k1[((size_t)e * Ff + kk) * 80 + co];
        } else if (o < 4160) {
            int kk = (o - 2560) / 80;
            v = r1[((size_t)e * Hh + kk) * 80 + co];
        } else if (o < 5760) {
            int kk = (o - 4160) / 80;
            v = k2[((size_t)e * Hh + kk) * 80 + co];
        } else {
            int kk = (o - 5760) / 80;
            v = r2[((size_t)e * Hh + kk) * 80 + co];
        }
    } else if (o < 7440) {
        int c = o - 7360, u = c >> 2;
        g = c & 3;
        v = b1[(size_t)e * 80 + g * 20 + u];
    } else {
        int c = o - 7440, u = c >> 2;
        g = c & 3;
        v = b2[(size_t)e * 80 + g * 20 + u];
    }
    if (g != 2) v *= LOG2E;     // sigmoid gates -> exp2 domain
    pw[idx] = v;
}

// ---------------------------------------------------------------- fused lstm + fc1
// 512 blocks x 256 thr, 2 blocks/CU; block i and i+256 land on the SAME CU, so the
// selector blockIdx.x<256 pairs one latency-bound LSTM block with one throughput
// fc1 block per CU (m114 co-scheduling).
//
// LSTM: swapped-operand MFMA + permuted k-map; h fully register-resident (no LDS).
// Layer-2 MFMA chain ordered stale-H2 first / fresh-H1 last so the cvt2->MFMA
// dependency gets ~3 MFMA latencies of slack.
//
// fc1: A operand direct global->reg->cvt2 (fragment = 2 contiguous float4 of one
// row), prefetched 1 step in private regs -- zero LDS, no barrier coupling.
// W operand double-buffered LDS (2x20KB), ONE barrier per 32-K step, W globals
// prefetched 2 steps ahead. W tile rows are 40 shorts (16B-aligned); the four 16B
// k-slots are swizzled: phys_slot = (logical + ((row>>3)&3)) & 3, making both the
// ds_write_b128 and ds_read_b128 patterns <=2-way (free per m136).
__global__ __launch_bounds__(256, 2) void fused_kernel(
    const unsigned short* __restrict__ xph, const unsigned short* __restrict__ xpl,
    const float* __restrict__ pw, const float* __restrict__ dw, const float* __restrict__ db,
    float* __restrict__ eo,
    const float* __restrict__ x, const float* __restrict__ W,
    const float* __restrict__ bias, float* __restrict__ C)
{
    __shared__ __align__(16) char smem[43008];

    if (blockIdx.x < 256) {
        // ================= LSTM path: wave w handles tile blockIdx.x*4+w =================
        const int l = threadIdx.x & 63;
        const int q = l >> 4, s = l & 15;
        const int tile = (blockIdx.x << 2) + (threadIdx.x >> 6);
        const int e = tile >> 6;
        const int c = tile & 63;
        const int b0 = c * 16;

        const float* Wm = pw + (size_t)e * PWE;
        bf16x8 K1h[5], K1l[5], R1h[5], R1l[5], K2h[5], K2l[5], R2h[5], R2l[5];
#pragma unroll
        for (int n = 0; n < 5; ++n) {
#pragma unroll
            for (int j = 0; j < 8; ++j) {
                int k8 = q * 8 + j;         // K1: x-feature k-map (32 features)
                int uk = 4 * j + q;         // R1/K2/R2: permuted h-unit k-map (j<5 valid)
                int cc = n * 16 + s;
                float wv_;
                unsigned short hi; float hf;
                wv_ = Wm[k8 * 80 + cc];
                hi = bf16_rne(wv_); hf = bf16_to_f(hi);
                K1h[n][j] = (short)hi; K1l[n][j] = (short)bf16_rne(wv_ - hf);
                wv_ = (j < 5) ? Wm[2560 + uk * 80 + cc] : 0.f;
                hi = bf16_rne(wv_); hf = bf16_to_f(hi);
                R1h[n][j] = (short)hi; R1l[n][j] = (short)bf16_rne(wv_ - hf);
                wv_ = (j < 5) ? Wm[4160 + uk * 80 + cc] : 0.f;
                hi = bf16_rne(wv_); hf = bf16_to_f(hi);
                K2h[n][j] = (short)hi; K2l[n][j] = (short)bf16_rne(wv_ - hf);
                wv_ = (j < 5) ? Wm[5760 + uk * 80 + cc] : 0.f;
                hi = bf16_rne(wv_); hf = bf16_to_f(hi);
                R2h[n][j] = (short)hi; R2l[n][j] = (short)bf16_rne(wv_ - hf);
            }
        }
        f32x4 bf1[5], bf2[5];
        float dwr[5];
#pragma unroll
        for (int n = 0; n < 5; ++n) {
            bf1[n] = *(const f32x4*)&Wm[7360 + n * 16 + 4 * q];
            bf2[n] = *(const f32x4*)&Wm[7440 + n * 16 + 4 * q];
            dwr[n] = dw[e * Hh + 4 * n + q];
        }

        float c1[5] = {0, 0, 0, 0, 0}, c2[5] = {0, 0, 0, 0, 0};
        float h2reg[5] = {0, 0, 0, 0, 0};

        const bf16x8 z8 = {0, 0, 0, 0, 0, 0, 0, 0};
        bf16x8 H1a = z8, H1b = z8, H2a = z8, H2b = z8;   // h[t-1] fragments, reg-resident

        const unsigned short* xbh = xph + (size_t)c * 65536 + l * 8;
        const unsigned short* xbl = xpl + (size_t)c * 65536 + l * 8;
        bf16x8 xch = *(const bf16x8*)xbh;
        bf16x8 xcl = *(const bf16x8*)xbl;

#pragma unroll 1
        for (int t = 0; t < Tt; ++t) {
            bf16x8 xnh = xch, xnl = xcl;
            if (t < Tt - 1) {       // prefetch t+1 (overlaps this step's compute)
                xnh = *(const bf16x8*)(xbh + (t + 1) * 512);
                xnl = *(const bf16x8*)(xbl + (t + 1) * 512);
            }

            // ---- layer 1: z^T = K1^T x^T + R1^T h1^T  (x first, fresh H1 last)
            f32x4 a1[5];
#pragma unroll
            for (int n = 0; n < 5; ++n) {
                f32x4 acc = bf1[n];
                acc = MFMA16(K1h[n], xch, acc);
                acc = MFMA16(K1l[n], xch, acc);
                acc = MFMA16(K1h[n], xcl, acc);
                acc = MFMA16(R1h[n], H1a, acc);
                acc = MFMA16(R1l[n], H1a, acc);
                acc = MFMA16(R1h[n], H1b, acc);
                a1[n] = acc;
            }
            {
                float hv[5];
#pragma unroll
                for (int n = 0; n < 5; ++n) {
                    float iv = sig2(a1[n][0]);
                    float fv = sig2(a1[n][1]);
                    float gv = fmaxf(a1[n][2], 0.f);
                    float ov = sig2(a1[n][3]);
                    c1[n] = fv * c1[n] + iv * gv;
                    hv[n] = ov * fmaxf(c1[n], 0.f);
                }
                unsigned h0, h1, h2, l0, l1, l2;
                cvt2(hv[0], hv[1], h0, l0);
                cvt2(hv[2], hv[3], h1, l1);
                cvt2(hv[4], 0.f,   h2, l2);
                u32x4 uh = {h0, h1, h2, 0u}, ul = {l0, l1, l2, 0u};
                H1a = __builtin_bit_cast(bf16x8, uh);
                H1b = __builtin_bit_cast(bf16x8, ul);
            }

            // ---- layer 2: stale H2 first, freshly-packed H1 last (cvt2 slack)
            f32x4 a2[5];
#pragma unroll
            for (int n = 0; n < 5; ++n) {
                f32x4 acc = bf2[n];
                acc = MFMA16(R2h[n], H2a, acc);
                acc = MFMA16(R2l[n], H2a, acc);
                acc = MFMA16(R2h[n], H2b, acc);
                acc = MFMA16(K2h[n], H1a, acc);
                acc = MFMA16(K2l[n], H1a, acc);
                acc = MFMA16(K2h[n], H1b, acc);
                a2[n] = acc;
            }
            {
                float hv[5];
#pragma unroll
                for (int n = 0; n < 5; ++n) {
                    float iv = sig2(a2[n][0]);
                    float fv = sig2(a2[n][1]);
                    float gv = fmaxf(a2[n][2], 0.f);
                    float ov = sig2(a2[n][3]);
                    c2[n] = fv * c2[n] + iv * gv;
                    float h = ov * fmaxf(c2[n], 0.f);
                    h2reg[n] = h;
                    hv[n] = h;
                }
                unsigned h0, h1, h2, l0, l1, l2;
                cvt2(hv[0], hv[1], h0, l0);
                cvt2(hv[2], hv[3], h1, l1);
                cvt2(hv[4], 0.f,   h2, l2);
                u32x4 uh = {h0, h1, h2, 0u}, ul = {l0, l1, l2, 0u};
                H2a = __builtin_bit_cast(bf16x8, uh);
                H2b = __builtin_bit_cast(bf16x8, ul);
            }

            xch = xnh; xcl = xnl;
        }

        float p = 0.f;
#pragma unroll
        for (int n = 0; n < 5; ++n) p += h2reg[n] * dwr[n];
        p += __shfl_xor(p, 16);
        p += __shfl_xor(p, 32);
        if (q == 0) eo[(size_t)e * Bsz + b0 + s] = db[e] + p;

    } else {
        // ================= fc1 path: 128x128, A-direct + W-dbuf =================
        const int tid = threadIdx.x;
        const int wv = tid >> 6, l = tid & 63, q = l >> 4, s = l & 15;
        const int id = blockIdx.x & 255;
        const int n0 = (id & 31) * 128, m0 = (id >> 5) * 128;
        const int wr = (wv & 1) * 64, wc = (wv >> 1) * 64;

        const int wn = tid & 127, wkq = tid >> 7;
        // physical slot for W stores: logical slots {2*wkq, 2*wkq+1}
        const int wrot = (wn >> 3) & 3;
        const int ws0 = ((wkq * 2) + wrot) & 3;
        const int ws1 = ((wkq * 2 + 1) + wrot) & 3;

        const float* WG = W + (size_t)(wkq * 16) * Dd + n0 + wn;
        const float* Arow = x + (size_t)(m0 + wr + s) * Dd + q * 8;

        unsigned short* lds = (unsigned short*)smem;   // [2][ Wsh 5120 | Wsl 5120 ]

        f32x4 acc[4][4];
#pragma unroll
        for (int mt = 0; mt < 4; ++mt)
#pragma unroll
            for (int nt = 0; nt < 4; ++nt) acc[mt][nt] = (f32x4){0.f, 0.f, 0.f, 0.f};

        float wfp[16];
        float4 afc[8];

        {   // prologue: W k-step0 -> buf0; W k-step1 -> wfp; A k-step0 -> afc
            float w0[16];
#pragma unroll
            for (int i = 0; i < 16; ++i) w0[i] = WG[(size_t)i * Dd];
            uint4 h0, l0, h1, l1;
            cvt2(w0[0],  w0[1],  h0.x, l0.x); cvt2(w0[2],  w0[3],  h0.y, l0.y);
            cvt2(w0[4],  w0[5],  h0.z, l0.z); cvt2(w0[6],  w0[7],  h0.w, l0.w);
            cvt2(w0[8],  w0[9],  h1.x, l1.x); cvt2(w0[10], w0[11], h1.y, l1.y);
            cvt2(w0[12], w0[13], h1.z, l1.z); cvt2(w0[14], w0[15], h1.w, l1.w);
            *(uint4*)&lds[wn * 40 + ws0 * 8]          = h0;
            *(uint4*)&lds[5120 + wn * 40 + ws0 * 8]   = l0;
            *(uint4*)&lds[wn * 40 + ws1 * 8]          = h1;
            *(uint4*)&lds[5120 + wn * 40 + ws1 * 8]   = l1;
#pragma unroll
            for (int i = 0; i < 16; ++i) wfp[i] = WG[(size_t)(32 + i) * Dd];
#pragma unroll
            for (int mt = 0; mt < 4; ++mt) {
                afc[mt * 2]     = *(const float4*)(Arow + (size_t)mt * 16 * Dd);
                afc[mt * 2 + 1] = *(const float4*)(Arow + (size_t)mt * 16 * Dd + 4);
            }
            __syncthreads();
        }

#pragma unroll 1
        for (int it = 0; it < 128; ++it) {
            const int k0 = it * 32;
            unsigned short* cb = lds + (it & 1) * 10240;        // compute buffer
            unsigned short* sb = lds + ((it & 1) ^ 1) * 10240;  // store buffer

            // phase 1: store W(k-step it+1) from wfp (loaded 1.5 steps ago)
            if (it < 127) {
                uint4 h0, l0, h1, l1;
                cvt2(wfp[0],  wfp[1],  h0.x, l0.x); cvt2(wfp[2],  wfp[3],  h0.y, l0.y);
                cvt2(wfp[4],  wfp[5],  h0.z, l0.z); cvt2(wfp[6],  wfp[7],  h0.w, l0.w);
                cvt2(wfp[8],  wfp[9],  h1.x, l1.x); cvt2(wfp[10], wfp[11], h1.y, l1.y);
                cvt2(wfp[12], wfp[13], h1.z, l1.z); cvt2(wfp[14], wfp[15], h1.w, l1.w);
                *(uint4*)&sb[wn * 40 + ws0 * 8]        = h0;
                *(uint4*)&sb[5120 + wn * 40 + ws0 * 8] = l0;
                *(uint4*)&sb[wn * 40 + ws1 * 8]        = h1;
                *(uint4*)&sb[5120 + wn * 40 + ws1 * 8] = l1;
            }

            // phase 2: issue W global loads for k-step it+2 (2 steps of cover)
            {
                const int kW = (it + 2 < 128) ? k0 + 64 : k0;
#pragma unroll
                for (int i = 0; i < 16; ++i) wfp[i] = WG[(size_t)(kW + i) * Dd];
            }

            // phase 3: W fragments from compute buffer (slot-swizzled)
            bf16x8 Wfh[4], Wfl[4];
#pragma unroll
            for (int nt = 0; nt < 4; ++nt) {
                const int row = wc + nt * 16 + s;
                const int ps = (q + ((row >> 3) & 3)) & 3;
                Wfh[nt] = *(bf16x8*)&cb[row * 40 + ps * 8];
                Wfl[nt] = *(bf16x8*)&cb[5120 + row * 40 + ps * 8];
            }

            // phase 4: A fragments from prefetched regs; issue A loads for it+1
            bf16x8 Afh[4], Afl[4];
#pragma unroll
            for (int mt = 0; mt < 4; ++mt) {
                uint4 uh, ul;
                cvt2(afc[mt * 2].x,     afc[mt * 2].y,     uh.x, ul.x);
                cvt2(afc[mt * 2].z,     afc[mt * 2].w,     uh.y, ul.y);
                cvt2(afc[mt * 2 + 1].x, afc[mt * 2 + 1].y, uh.z, ul.z);
                cvt2(afc[mt * 2 + 1].z, afc[mt * 2 + 1].w, uh.w, ul.w);
                Afh[mt] = __builtin_bit_cast(bf16x8, uh);
                Afl[mt] = __builtin_bit_cast(bf16x8, ul);
            }
            {
                const int kA = (it + 1 < 128) ? k0 + 32 : k0;
#pragma unroll
                for (int mt = 0; mt < 4; ++mt) {
                    afc[mt * 2]     = *(const float4*)(Arow + (size_t)mt * 16 * Dd + kA);
                    afc[mt * 2 + 1] = *(const float4*)(Arow + (size_t)mt * 16 * Dd + kA + 4);
                }
            }

            // phase 5: MFMA
#pragma unroll
            for (int mt = 0; mt < 4; ++mt)
#pragma unroll
                for (int nt = 0; nt < 4; ++nt) {
                    f32x4 a = acc[mt][nt];
                    a = MFMA16(Afl[mt], Wfh[nt], a);
                    a = MFMA16(Afh[mt], Wfl[nt], a);
                    a = MFMA16(Afh[mt], Wfh[nt], a);
                    acc[mt][nt] = a;
                }

            // phase 6: one barrier per step (store->read and read->overwrite fences)
            __syncthreads();
        }

#pragma unroll
        for (int nt = 0; nt < 4; ++nt) {
            float bv = bias[n0 + wc + nt * 16 + s];
#pragma unroll
            for (int mt = 0; mt < 4; ++mt)
#pragma unroll
                for (int r = 0; r < 4; ++r) {
                    int m = m0 + wr + mt * 16 + q * 4 + r;
                    C[(size_t)m * Dd + n0 + wc + nt * 16 + s] = fmaxf(acc[mt][nt][r] + bv, 0.f);
                }
        }
    }
}

// ---------------------------------------------------------------- gate: softmax(g @ gate_w + gb) + combine
__global__ __launch_bounds__(256) void gate_kernel(const float* __restrict__ g,
                                                   const float* __restrict__ gw,
                                                   const float* __restrict__ gb,
                                                   const float* __restrict__ eo,
                                                   float* __restrict__ out)
{
    int b = blockIdx.x;
    int tid = threadIdx.x;
    int lane = tid & 63;
    int wv = tid >> 6;

    float acc[16];
#pragma unroll
    for (int j = 0; j < 16; ++j) acc[j] = 0.f;

    const float* grow = g + (size_t)b * Dd;
#pragma unroll
    for (int it = 0; it < Dd / 256; ++it) {
        int d = tid + it * 256;
        float gv = grow[d];
        const float4* wr = (const float4*)(gw + (size_t)d * 16);
        float4 w0 = wr[0], w1 = wr[1], w2 = wr[2], w3 = wr[3];
        acc[0] += gv * w0.x;  acc[1] += gv * w0.y;  acc[2] += gv * w0.z;  acc[3] += gv * w0.w;
        acc[4] += gv * w1.x;  acc[5] += gv * w1.y;  acc[6] += gv * w1.z;  acc[7] += gv * w1.w;
        acc[8] += gv * w2.x;  acc[9] += gv * w2.y;  acc[10] += gv * w2.z; acc[11] += gv * w2.w;
        acc[12] += gv * w3.x; acc[13] += gv * w3.y; acc[14] += gv * w3.z; acc[15] += gv * w3.w;
    }

    __shared__ float red[64];
    __shared__ float logits[16];
#pragma unroll
    for (int j = 0; j < 16; ++j) {
        float v = acc[j];
#pragma unroll
        for (int m = 32; m >= 1; m >>= 1) v += __shfl_xor(v, m);
        if (lane == 0) red[wv * 16 + j] = v;
    }
    __syncthreads();
    if (tid < 16) {
        logits[tid] = gb[tid] + red[tid] + red[16 + tid] + red[32 + tid] + red[48 + tid];
    }
    __syncthreads();
    if (tid == 0) {
        float m = logits[0];
#pragma unroll
        for (int j = 1; j < 16; ++j) m = fmaxf(m, logits[j]);
        float ex[16], ssum = 0.f;
#pragma unroll
        for (int j = 0; j < 16; ++j) { ex[j] = __expf(logits[j] - m); ssum += ex[j]; }
        float inv = 1.f / ssum;
        float o = 0.f;
#pragma unroll
        for (int j = 0; j < 16; ++j) o += ex[j] * inv * eo[(size_t)j * Bsz + b];
        out[b] = o;
    }
}

// ----------------------------------------------------------------
extern "C" void kernel_launch(void* const* d_in, const int* in_sizes, int n_in,
                              void* d_out, int out_size, void* d_ws, size_t ws_size,
                              hipStream_t stream)
{
    const float* x     = (const float*)d_in[0];
    const float* gamma = (const float*)d_in[1];
    const float* beta  = (const float*)d_in[2];
    const float* mean  = (const float*)d_in[3];
    const float* var   = (const float*)d_in[4];
    const float* k1    = (const float*)d_in[5];
    const float* r1    = (const float*)d_in[6];
    const float* b1    = (const float*)d_in[7];
    const float* k2    = (const float*)d_in[8];
    const float* r2    = (const float*)d_in[9];
    const float* b2    = (const float*)d_in[10];
    const float* dw    = (const float*)d_in[11];
    const float* db    = (const float*)d_in[12];
    const float* fc1w  = (const float*)d_in[13];
    const float* fc1b  = (const float*)d_in[14];
    const float* gw    = (const float*)d_in[15];
    const float* gb    = (const float*)d_in[16];
    float* out = (float*)d_out;

    // workspace: 33.1 MB (<= previously-proven 34.2 MB footprint)
    float* g = (float*)d_ws;                                        // 4,194,304 f (16 MB)
    unsigned short* xph = (unsigned short*)(g + (size_t)Bsz * Dd);  // 8 MB
    unsigned short* xpl = xph + (size_t)Bsz * Dd / 2 * 2;           // 8 MB
    float* pw  = (float*)(xpl + (size_t)4194304);                   // 120,320 f
    float* eo  = pw + (size_t)Ee * PWE;                             // 16,384 f

    xpack_kernel<<<2048, 256, 0, stream>>>(x, gamma, beta, mean, var, xph, xpl);
    repack2_kernel<<<(Ee * PWE + 255) / 256, 256, 0, stream>>>(k1, r1, b1, k2, r2, b2, pw);
    fused_kernel<<<512, 256, 0, stream>>>(xph, xpl, pw, dw, db, eo, x, fc1w, fc1b, g);
    gate_kernel<<<Bsz, 256, 0, stream>>>(g, gw, gb, eo, out);
}